// Round 2
// baseline (159.600 us; speedup 1.0000x reference)
//
#include <hip/hip_runtime.h>

// SnakeBrain fused kernel, round 2: LDS-traffic restructure.
// One block (256 thr) per snake; thread i = node i.
// Key changes vs round 1 (which was DS-pipe-bound at ~50us of b32 traffic):
//  - stencil1 applied on 2-channel x BEFORE W1 (S and W commute): kills 128 b32 ops/thread
//  - quad-major float4 LDS layout -> all exchange is conflict-free ds_*_b128
//  - stencil2 reads only the 2 neighbor rows (own row kept in registers)
//  - pool: 8 b128 reads + shfl_xor halving reduction (no 2nd LDS round-trip)

#define NB  4096
#define CL  256
#define HID 32
#define FIN 64
#define NQ  (HID / 4)   // 8 channel quads

__global__ __launch_bounds__(256) void snake_fused(
    const float* __restrict__ x,
    const float* __restrict__ heads,
    const float* __restrict__ body_sizes,
    const float* __restrict__ fruits,
    const float* __restrict__ W1, const float* __restrict__ b1,
    const float* __restrict__ W2, const float* __restrict__ b2,
    const float* __restrict__ Wr, const float* __restrict__ br,
    const float* __restrict__ Wa1, const float* __restrict__ ba1,
    const float* __restrict__ Wa2, const float* __restrict__ ba2,
    const float* __restrict__ Wc, const float* __restrict__ bc,
    const float* __restrict__ Wp, const float* __restrict__ bp,
    const float* __restrict__ Wv, const float* __restrict__ bv,
    float* __restrict__ out)
{
    __shared__ float4 hq[NQ][CL];     // 32 KB quad-major node features
    __shared__ float4 pooled4[NQ];    // 32 pooled channels
    __shared__ float  catbuf[FIN];    // [body_emb | aux2]
    __shared__ float  auxbuf[HID];    // aux1
    __shared__ float  cmb[FIN];

    const int b = blockIdx.x;
    const int i = threadIdx.x;

    // GCN norm coefficients (deg incl. self-loop: 3 interior, 2 at ends)
    const float INV_S3 = 0.57735026918962576f;
    const float INV_S2 = 0.70710678118654752f;
    const float di   = (i == 0 || i == CL - 1) ? INV_S2 : INV_S3;
    const float dil  = (i == 1)      ? INV_S2 : INV_S3;
    const float dirr = (i == CL - 2) ? INV_S2 : INV_S3;
    const float nc = di * di;
    const float nl = (i > 0)      ? di * dil  : 0.0f;
    const float nr = (i < CL - 1) ? di * dirr : 0.0f;
    const int il = (i > 0)      ? i - 1 : i;
    const int ir = (i < CL - 1) ? i + 1 : i;

    // ---- phase 1: stencil on x (2 channels), then W1 ----
    // S(x@W1) == (Sx)@W1 : apply node-mixing on the 2-ch input, not the 32-ch hidden
    float2* xb = reinterpret_cast<float2*>(&hq[0][0]);  // alias: hq unused yet
    xb[i] = reinterpret_cast<const float2*>(x)[b * CL + i];
    __syncthreads();
    const float2 xc = xb[i];
    const float2 xl = xb[il];
    const float2 xr = xb[ir];
    __syncthreads();  // xb reads done before hq reuse

    const float sxx = nc * xc.x + nl * xl.x + nr * xr.x;
    const float sxy = nc * xc.y + nl * xl.y + nr * xr.y;

    float r1[HID];
    #pragma unroll
    for (int c = 0; c < HID; ++c) {
        float v = fmaf(sxx, W1[c], fmaf(sxy, W1[HID + c], b1[c]));
        r1[c] = fmaxf(v, 0.0f);
    }

    // ---- layer 2 matmul: acc = r1 @ W2 (32x32), pure registers ----
    float acc[HID];
    #pragma unroll
    for (int c = 0; c < HID; ++c) acc[c] = 0.0f;
    const float4* W24 = reinterpret_cast<const float4*>(W2);
    #pragma unroll 4
    for (int k = 0; k < HID; ++k) {
        const float rk = r1[k];
        #pragma unroll
        for (int c4 = 0; c4 < NQ; ++c4) {
            const float4 w = W24[k * NQ + c4];
            acc[4 * c4 + 0] = fmaf(rk, w.x, acc[4 * c4 + 0]);
            acc[4 * c4 + 1] = fmaf(rk, w.y, acc[4 * c4 + 1]);
            acc[4 * c4 + 2] = fmaf(rk, w.z, acc[4 * c4 + 2]);
            acc[4 * c4 + 3] = fmaf(rk, w.w, acc[4 * c4 + 3]);
        }
    }

    // ---- publish acc for stencil2 (8x ds_write_b128, conflict-free) ----
    #pragma unroll
    for (int q = 0; q < NQ; ++q)
        hq[q][i] = make_float4(acc[4 * q], acc[4 * q + 1], acc[4 * q + 2], acc[4 * q + 3]);
    __syncthreads();

    // ---- stencil2: neighbors from LDS (16x b128), own from registers ----
    const float4* b24 = reinterpret_cast<const float4*>(b2);
    #pragma unroll
    for (int q = 0; q < NQ; ++q) {
        const float4 aL = hq[q][il];
        const float4 aR = hq[q][ir];
        const float4 bq = b24[q];
        acc[4 * q + 0] = fmaxf(nc * acc[4 * q + 0] + nl * aL.x + nr * aR.x + bq.x, 0.0f);
        acc[4 * q + 1] = fmaxf(nc * acc[4 * q + 1] + nl * aL.y + nr * aR.y + bq.y, 0.0f);
        acc[4 * q + 2] = fmaxf(nc * acc[4 * q + 2] + nl * aL.z + nr * aR.z + bq.z, 0.0f);
        acc[4 * q + 3] = fmaxf(nc * acc[4 * q + 3] + nl * aL.w + nr * aR.w + bq.w, 0.0f);
    }
    __syncthreads();  // all stencil2 reads done before overwrite

    // ---- publish h2 for pooling ----
    #pragma unroll
    for (int q = 0; q < NQ; ++q)
        hq[q][i] = make_float4(acc[4 * q], acc[4 * q + 1], acc[4 * q + 2], acc[4 * q + 3]);
    __syncthreads();

    // ---- mean pool: thread (q=i>>5, j=i&31) sums its quad over 8 node-slots,
    //      then shfl_xor halving over the 32 j-lanes (masks stay within half-wave) ----
    {
        const int q = i >> 5;
        const int j = i & 31;
        float4 s = make_float4(0.f, 0.f, 0.f, 0.f);
        #pragma unroll
        for (int t = 0; t < 8; ++t) {
            const float4 v = hq[q][j + 32 * t];
            s.x += v.x; s.y += v.y; s.z += v.z; s.w += v.w;
        }
        #pragma unroll
        for (int m = 1; m <= 16; m <<= 1) {
            s.x += __shfl_xor(s.x, m, 64);
            s.y += __shfl_xor(s.y, m, 64);
            s.z += __shfl_xor(s.z, m, 64);
            s.w += __shfl_xor(s.w, m, 64);
        }
        if (j == 0) {
            const float inv = 1.0f / 256.0f;
            pooled4[q] = make_float4(s.x * inv, s.y * inv, s.z * inv, s.w * inv);
        }
    }
    __syncthreads();

    // ---- head phase A: body_emb (lanes 0-31, no relu) || aux1 (lanes 32-63) ----
    if (i < HID) {
        const float* pl = reinterpret_cast<const float*>(pooled4);
        float be = br[i];
        #pragma unroll 8
        for (int k = 0; k < HID; ++k)
            be = fmaf(pl[k], Wr[k * HID + i], be);
        catbuf[i] = be;
    } else if (i < 2 * HID) {
        const int c = i - HID;
        const float a0 = heads[2 * b];
        const float a1 = heads[2 * b + 1];
        const float a2 = body_sizes[b];
        const float a3 = fruits[2 * b];
        const float a4 = fruits[2 * b + 1];
        float a = ba1[c];
        a = fmaf(a0, Wa1[0 * HID + c], a);
        a = fmaf(a1, Wa1[1 * HID + c], a);
        a = fmaf(a2, Wa1[2 * HID + c], a);
        a = fmaf(a3, Wa1[3 * HID + c], a);
        a = fmaf(a4, Wa1[4 * HID + c], a);
        auxbuf[c] = fmaxf(a, 0.0f);
    }
    __syncthreads();

    // ---- head phase B: aux layer-2 ----
    if (i < HID) {
        float a = ba2[i];
        #pragma unroll 8
        for (int k = 0; k < HID; ++k)
            a = fmaf(auxbuf[k], Wa2[k * HID + i], a);
        catbuf[HID + i] = fmaxf(a, 0.0f);
    }
    __syncthreads();

    // ---- head phase C: combined = relu(cat @ Wc + bc) ----
    if (i < FIN) {
        float cb = bc[i];
        #pragma unroll 8
        for (int k = 0; k < FIN; ++k)
            cb = fmaf(catbuf[k], Wc[k * FIN + i], cb);
        cmb[i] = fmaxf(cb, 0.0f);
    }
    __syncthreads();

    // ---- head phase D: logits (5) + value (1) ----
    if (i < 5) {
        float lg = bp[i];
        #pragma unroll 8
        for (int k = 0; k < FIN; ++k)
            lg = fmaf(cmb[k], Wp[k * 5 + i], lg);
        out[b * 5 + i] = lg;
    } else if (i == 5) {
        float vv = bv[0];
        #pragma unroll 8
        for (int k = 0; k < FIN; ++k)
            vv = fmaf(cmb[k], Wv[k], vv);
        out[NB * 5 + b] = vv;
    }
}

extern "C" void kernel_launch(void* const* d_in, const int* in_sizes, int n_in,
                              void* d_out, int out_size, void* d_ws, size_t ws_size,
                              hipStream_t stream) {
    const float* x          = (const float*)d_in[0];
    const float* heads      = (const float*)d_in[1];
    const float* body_sizes = (const float*)d_in[2];
    const float* fruits     = (const float*)d_in[3];
    const float* W1 = (const float*)d_in[4];
    const float* b1 = (const float*)d_in[5];
    const float* W2 = (const float*)d_in[6];
    const float* b2 = (const float*)d_in[7];
    const float* Wr = (const float*)d_in[8];
    const float* br = (const float*)d_in[9];
    const float* Wa1 = (const float*)d_in[10];
    const float* ba1 = (const float*)d_in[11];
    const float* Wa2 = (const float*)d_in[12];
    const float* ba2 = (const float*)d_in[13];
    const float* Wc = (const float*)d_in[14];
    const float* bc = (const float*)d_in[15];
    const float* Wp = (const float*)d_in[16];
    const float* bp = (const float*)d_in[17];
    const float* Wv = (const float*)d_in[18];
    const float* bv = (const float*)d_in[19];

    float* out = (float*)d_out;
    snake_fused<<<NB, CL, 0, stream>>>(
        x, heads, body_sizes, fruits,
        W1, b1, W2, b2, Wr, br, Wa1, ba1, Wa2, ba2,
        Wc, bc, Wp, bp, Wv, bv, out);
}

// Round 3
// 158.367 us; speedup vs baseline: 1.0078x; 1.0078x over previous
//
#include <hip/hip_runtime.h>

// SnakeBrain fused kernel, round 3: occupancy + latency-hiding.
// Round-2 post-mortem: kernel is latency-bound (VALUBusy 44%, all pipes idle,
// 4 waves/SIMD). Fix: LDS <= 17 KB -> 8 blocks/CU (8 waves/SIMD), in-place
// stencil2 to keep VGPR <= 64, wave0-solo head with shfl (no barriers, early
// retire of waves 1-3).

#define NB  4096
#define CL  256
#define HID 32
#define FIN 64

__global__ __launch_bounds__(256, 8) void snake_fused(
    const float* __restrict__ x,
    const float* __restrict__ heads,
    const float* __restrict__ body_sizes,
    const float* __restrict__ fruits,
    const float* __restrict__ W1, const float* __restrict__ b1,
    const float* __restrict__ W2, const float* __restrict__ b2,
    const float* __restrict__ Wr, const float* __restrict__ br,
    const float* __restrict__ Wa1, const float* __restrict__ ba1,
    const float* __restrict__ Wa2, const float* __restrict__ ba2,
    const float* __restrict__ Wc, const float* __restrict__ bc,
    const float* __restrict__ Wp, const float* __restrict__ bp,
    const float* __restrict__ Wv, const float* __restrict__ bv,
    float* __restrict__ out)
{
    __shared__ float4 bufA[4][CL];   // 16 KB, reused: x-exchange, stencil halves, pool
    __shared__ float4 pooled4[HID / 4];

    const int b = blockIdx.x;
    const int i = threadIdx.x;

    // GCN norm coefficients (deg incl. self-loop: 3 interior, 2 at ends)
    const float INV_S3 = 0.57735026918962576f;
    const float INV_S2 = 0.70710678118654752f;
    const float di   = (i == 0 || i == CL - 1) ? INV_S2 : INV_S3;
    const float dil  = (i == 1)      ? INV_S2 : INV_S3;
    const float dirr = (i == CL - 2) ? INV_S2 : INV_S3;
    const float nc = di * di;
    const float nl = (i > 0)      ? di * dil  : 0.0f;
    const float nr = (i < CL - 1) ? di * dirr : 0.0f;
    const int il = (i > 0)      ? i - 1 : i;
    const int ir = (i < CL - 1) ? i + 1 : i;

    // ---- stencil on 2-ch input x (S and W1 commute) ----
    float2* xb = reinterpret_cast<float2*>(bufA);
    xb[i] = reinterpret_cast<const float2*>(x)[b * CL + i];
    __syncthreads();
    const float2 xc = xb[i];
    const float2 xl = xb[il];
    const float2 xr = xb[ir];
    __syncthreads();  // xb dead; bufA free

    const float sxx = nc * xc.x + nl * xl.x + nr * xr.x;
    const float sxy = nc * xc.y + nl * xl.y + nr * xr.y;

    // ---- fused layer1 + layer2 matmul: acc = relu((Sx)@W1 + b1) @ W2 ----
    // r1[k] materialized per-iteration (keeps live VGPRs ~= acc[32] only).
    // W2 offsets are compile-time constants -> scalar-load candidates.
    float acc[HID];
    #pragma unroll
    for (int c = 0; c < HID; ++c) acc[c] = 0.0f;
    const float4* W24 = reinterpret_cast<const float4*>(W2);
    #pragma unroll
    for (int k = 0; k < HID; ++k) {
        const float rk = fmaxf(fmaf(sxx, W1[k], fmaf(sxy, W1[HID + k], b1[k])), 0.0f);
        #pragma unroll
        for (int c4 = 0; c4 < HID / 4; ++c4) {
            const float4 w = W24[k * (HID / 4) + c4];
            acc[4 * c4 + 0] = fmaf(rk, w.x, acc[4 * c4 + 0]);
            acc[4 * c4 + 1] = fmaf(rk, w.y, acc[4 * c4 + 1]);
            acc[4 * c4 + 2] = fmaf(rk, w.z, acc[4 * c4 + 2]);
            acc[4 * c4 + 3] = fmaf(rk, w.w, acc[4 * c4 + 3]);
        }
    }

    // ---- stencil2 + relu + mean-pool, two 4-quad passes through bufA ----
    const float4* b24 = reinterpret_cast<const float4*>(b2);
    #pragma unroll
    for (int h = 0; h < 2; ++h) {
        // publish this half's pre-stencil values
        #pragma unroll
        for (int q = 0; q < 4; ++q) {
            const int c = 16 * h + 4 * q;
            bufA[q][i] = make_float4(acc[c], acc[c + 1], acc[c + 2], acc[c + 3]);
        }
        __syncthreads();
        // stencil2 in place (own value from regs, neighbors from LDS)
        #pragma unroll
        for (int q = 0; q < 4; ++q) {
            const float4 aL = bufA[q][il];
            const float4 aR = bufA[q][ir];
            const float4 bq = b24[4 * h + q];
            const int c = 16 * h + 4 * q;
            acc[c + 0] = fmaxf(fmaf(nc, acc[c + 0], fmaf(nl, aL.x, fmaf(nr, aR.x, bq.x))), 0.0f);
            acc[c + 1] = fmaxf(fmaf(nc, acc[c + 1], fmaf(nl, aL.y, fmaf(nr, aR.y, bq.y))), 0.0f);
            acc[c + 2] = fmaxf(fmaf(nc, acc[c + 2], fmaf(nl, aL.z, fmaf(nr, aR.z, bq.z))), 0.0f);
            acc[c + 3] = fmaxf(fmaf(nc, acc[c + 3], fmaf(nl, aL.w, fmaf(nr, aR.w, bq.w))), 0.0f);
        }
        __syncthreads();  // neighbor reads done before overwrite
        // publish h2 half for pooling
        #pragma unroll
        for (int q = 0; q < 4; ++q) {
            const int c = 16 * h + 4 * q;
            bufA[q][i] = make_float4(acc[c], acc[c + 1], acc[c + 2], acc[c + 3]);
        }
        __syncthreads();
        // pool: wave w sums quad w over its 64-node strips + butterfly
        {
            const int w = i >> 6;
            const int j = i & 63;
            float4 s = make_float4(0.f, 0.f, 0.f, 0.f);
            #pragma unroll
            for (int t = 0; t < 4; ++t) {
                const float4 v = bufA[w][j + 64 * t];
                s.x += v.x; s.y += v.y; s.z += v.z; s.w += v.w;
            }
            #pragma unroll
            for (int m = 1; m <= 32; m <<= 1) {
                s.x += __shfl_xor(s.x, m, 64);
                s.y += __shfl_xor(s.y, m, 64);
                s.z += __shfl_xor(s.z, m, 64);
                s.w += __shfl_xor(s.w, m, 64);
            }
            if (j == 0) {
                const float inv = 1.0f / 256.0f;
                pooled4[4 * h + w] = make_float4(s.x * inv, s.y * inv, s.z * inv, s.w * inv);
            }
        }
        __syncthreads();  // pooled visible; bufA free for next half
    }

    // ---- head: wave 0 only, zero barriers, shfl exchange. Waves 1-3 retire. ----
    if (i < 64) {
        const float* pooled = reinterpret_cast<const float*>(pooled4);
        float catv;
        if (i < HID) {
            // body_emb = pooled @ Wr + br   (no relu)
            float be = br[i];
            #pragma unroll 8
            for (int k = 0; k < HID; ++k)
                be = fmaf(pooled[k], Wr[k * HID + i], be);
            catv = be;
        } else {
            // aux chain, lanes 32-63
            const int c = i - HID;
            float a = ba1[c];
            a = fmaf(heads[2 * b],      Wa1[0 * HID + c], a);
            a = fmaf(heads[2 * b + 1],  Wa1[1 * HID + c], a);
            a = fmaf(body_sizes[b],     Wa1[2 * HID + c], a);
            a = fmaf(fruits[2 * b],     Wa1[3 * HID + c], a);
            a = fmaf(fruits[2 * b + 1], Wa1[4 * HID + c], a);
            a = fmaxf(a, 0.0f);  // aux1 in lanes 32-63
            float a2 = ba2[c];
            #pragma unroll 8
            for (int k = 0; k < HID; ++k)
                a2 = fmaf(__shfl(a, HID + k, 64), Wa2[k * HID + c], a2);
            catv = fmaxf(a2, 0.0f);
        }
        // combined channel i = relu( sum_k cat[k] * Wc[k][i] + bc[i] )
        float cb = bc[i];
        #pragma unroll 8
        for (int k = 0; k < FIN; ++k)
            cb = fmaf(__shfl(catv, k, 64), Wc[k * FIN + i], cb);
        cb = fmaxf(cb, 0.0f);
        // logits + value: outer-product partials + butterfly reduce
        float s0 = cb * Wp[i * 5 + 0];
        float s1 = cb * Wp[i * 5 + 1];
        float s2 = cb * Wp[i * 5 + 2];
        float s3 = cb * Wp[i * 5 + 3];
        float s4 = cb * Wp[i * 5 + 4];
        float s5 = cb * Wv[i];
        #pragma unroll
        for (int m = 1; m <= 32; m <<= 1) {
            s0 += __shfl_xor(s0, m, 64);
            s1 += __shfl_xor(s1, m, 64);
            s2 += __shfl_xor(s2, m, 64);
            s3 += __shfl_xor(s3, m, 64);
            s4 += __shfl_xor(s4, m, 64);
            s5 += __shfl_xor(s5, m, 64);
        }
        if (i == 0) {
            out[b * 5 + 0] = s0 + bp[0];
            out[b * 5 + 1] = s1 + bp[1];
            out[b * 5 + 2] = s2 + bp[2];
            out[b * 5 + 3] = s3 + bp[3];
            out[b * 5 + 4] = s4 + bp[4];
            out[NB * 5 + b] = s5 + bv[0];
        }
    }
}

extern "C" void kernel_launch(void* const* d_in, const int* in_sizes, int n_in,
                              void* d_out, int out_size, void* d_ws, size_t ws_size,
                              hipStream_t stream) {
    const float* x          = (const float*)d_in[0];
    const float* heads      = (const float*)d_in[1];
    const float* body_sizes = (const float*)d_in[2];
    const float* fruits     = (const float*)d_in[3];
    const float* W1 = (const float*)d_in[4];
    const float* b1 = (const float*)d_in[5];
    const float* W2 = (const float*)d_in[6];
    const float* b2 = (const float*)d_in[7];
    const float* Wr = (const float*)d_in[8];
    const float* br = (const float*)d_in[9];
    const float* Wa1 = (const float*)d_in[10];
    const float* ba1 = (const float*)d_in[11];
    const float* Wa2 = (const float*)d_in[12];
    const float* ba2 = (const float*)d_in[13];
    const float* Wc = (const float*)d_in[14];
    const float* bc = (const float*)d_in[15];
    const float* Wp = (const float*)d_in[16];
    const float* bp = (const float*)d_in[17];
    const float* Wv = (const float*)d_in[18];
    const float* bv = (const float*)d_in[19];

    float* out = (float*)d_out;
    snake_fused<<<NB, CL, 0, stream>>>(
        x, heads, body_sizes, fruits,
        W1, b1, W2, b2, Wr, br, Wa1, ba1, Wa2, ba2,
        Wc, bc, Wp, bp, Wv, bv, out);
}

// Round 4
// 141.644 us; speedup vs baseline: 1.1268x; 1.1181x over previous
//
#include <hip/hip_runtime.h>

// SnakeBrain fused kernel, round 4: MFMA for the dominant 32x32 matmul.
// R3 post-mortem: VALU-issue-bound (~1800 instr/thread) + launch_bounds(256,8)
// caused register spills (WRITE_SIZE 320->2368 KB). Fix: move r1@W2 to
// mfma_f32_16x16x32_bf16 with split-bf16 (3 terms, err ~3e-5 << 4.45e-3
// threshold); stencil2+pool directly on C/D-layout regs via shfl; (256,6).

#define NB  4096
#define CL  256
#define HID 32
#define FIN 64

typedef __attribute__((ext_vector_type(8))) short bf16x8;
typedef __attribute__((ext_vector_type(4))) float f32x4;

__device__ __forceinline__ unsigned short f2bf(float f) {
    unsigned u = __builtin_bit_cast(unsigned, f);
    u += 0x7FFFu + ((u >> 16) & 1u);          // round-to-nearest-even
    return (unsigned short)(u >> 16);
}
__device__ __forceinline__ float bf2f(unsigned short h) {
    unsigned u = ((unsigned)h) << 16;
    return __builtin_bit_cast(float, u);
}
// GCN chain coefficients for node n (deg incl self-loop: 3 interior, 2 ends)
__device__ __forceinline__ void gcn_coef(int n, float& nc, float& nl, float& nr) {
    const float IS3 = 0.57735026918962576f, IS2 = 0.70710678118654752f;
    const float dn = (n == 0 || n == CL - 1) ? IS2 : IS3;
    nc = dn * dn;
    nl = (n > 0)      ? dn * ((n == 1)      ? IS2 : IS3) : 0.0f;
    nr = (n < CL - 1) ? dn * ((n == CL - 2) ? IS2 : IS3) : 0.0f;
}

__global__ __launch_bounds__(256, 6) void snake_fused(
    const float* __restrict__ x,
    const float* __restrict__ heads,
    const float* __restrict__ body_sizes,
    const float* __restrict__ fruits,
    const float* __restrict__ W1, const float* __restrict__ b1,
    const float* __restrict__ W2, const float* __restrict__ b2,
    const float* __restrict__ Wr, const float* __restrict__ br,
    const float* __restrict__ Wa1, const float* __restrict__ ba1,
    const float* __restrict__ Wa2, const float* __restrict__ ba2,
    const float* __restrict__ Wc, const float* __restrict__ bc,
    const float* __restrict__ Wp, const float* __restrict__ bp,
    const float* __restrict__ Wv, const float* __restrict__ bv,
    float* __restrict__ out)
{
    // A-matrix staging: 256 nodes x 32 bf16, row stride 40 shorts (80 B) so
    // frag reads/writes are 16B-aligned and ~2-way-bank-spread. Reused for the
    // hi pass then the lo pass. Also aliased for the initial x exchange.
    __shared__ short Abuf[CL * 40];            // 20480 B
    __shared__ float edgebuf[4][2][HID];       // wave-boundary h2pre rows
    __shared__ float waveparts[4][HID];        // pooling partials

    const int b = blockIdx.x;
    const int i = threadIdx.x;
    const int w    = i >> 6;        // wave id: nodes 64w..64w+63
    const int lane = i & 63;
    const int g    = lane >> 4;     // k-quad / row-group
    const int c    = lane & 15;     // tile col

    // ---- B fragments for W2 (split bf16), same for all blocks -> L2-hot ----
    // mfma_f32_16x16x32_bf16 B layout: B[k = 8*(lane>>4)+j][n = lane&15]
    bf16x8 Bh[2], Bl[2];
    #pragma unroll
    for (int nt = 0; nt < 2; ++nt) {
        #pragma unroll
        for (int j = 0; j < 8; ++j) {
            const float wv = W2[(8 * g + j) * HID + c + 16 * nt];
            const unsigned short h = f2bf(wv);
            Bh[nt][j] = (short)h;
            Bl[nt][j] = (short)f2bf(wv - bf2f(h));
        }
    }
    const float b2v0 = b2[c];
    const float b2v1 = b2[c + 16];

    // ---- stencil on 2-ch input x (S and W1 commute) ----
    float ncd, nld, nrd;
    gcn_coef(i, ncd, nld, nrd);
    const int il = (i > 0) ? i - 1 : i;
    const int ir = (i < CL - 1) ? i + 1 : i;
    float2* xb = reinterpret_cast<float2*>(Abuf);
    xb[i] = reinterpret_cast<const float2*>(x)[b * CL + i];
    __syncthreads();
    const float2 xc = xb[i];
    const float2 xl = xb[il];
    const float2 xr = xb[ir];
    __syncthreads();  // xb dead; Abuf free for A staging
    const float sxx = ncd * xc.x + nld * xl.x + nrd * xr.x;
    const float sxy = ncd * xc.y + nld * xl.y + nrd * xr.y;

    // ---- r1 = relu((Sx)@W1 + b1), split to bf16 hi/lo ----
    bf16x8 hv[4], lv[4];
    #pragma unroll
    for (int s = 0; s < 4; ++s) {
        #pragma unroll
        for (int j = 0; j < 8; ++j) {
            const int ch = 8 * s + j;
            const float r = fmaxf(fmaf(sxx, W1[ch], fmaf(sxy, W1[HID + ch], b1[ch])), 0.0f);
            const unsigned short h = f2bf(r);
            hv[s][j] = (short)h;
            lv[s][j] = (short)f2bf(r - bf2f(h));
        }
    }
    {   // publish A_hi: node i's 32 bf16 at row stride 40 shorts
        bf16x8* ap = reinterpret_cast<bf16x8*>(&Abuf[i * 40]);
        #pragma unroll
        for (int s = 0; s < 4; ++s) ap[s] = hv[s];
    }
    __syncthreads();

    // ---- GEMM: h2pre(256x32) = r1 @ W2, 3-term split-bf16 MFMA ----
    // A layout: A[m = lane&15][k = 8*(lane>>4)+j]; C/D: col=lane&15,
    // row=(lane>>4)*4+reg. Wave w covers m-tiles t: nodes 64w+16t..+15.
    f32x4 acc[4][2];
    #pragma unroll
    for (int t = 0; t < 4; ++t) {
        #pragma unroll
        for (int nt = 0; nt < 2; ++nt) { f32x4 z = {0.f, 0.f, 0.f, 0.f}; acc[t][nt] = z; }
    }
    #pragma unroll
    for (int t = 0; t < 4; ++t) {
        const int node = 64 * w + 16 * t + c;
        const bf16x8 a = *reinterpret_cast<const bf16x8*>(&Abuf[node * 40 + 8 * g]);
        #pragma unroll
        for (int nt = 0; nt < 2; ++nt) {
            acc[t][nt] = __builtin_amdgcn_mfma_f32_16x16x32_bf16(a, Bh[nt], acc[t][nt], 0, 0, 0);
            acc[t][nt] = __builtin_amdgcn_mfma_f32_16x16x32_bf16(a, Bl[nt], acc[t][nt], 0, 0, 0);
        }
    }
    __syncthreads();   // all hi-frag reads done
    {   // publish A_lo
        bf16x8* ap = reinterpret_cast<bf16x8*>(&Abuf[i * 40]);
        #pragma unroll
        for (int s = 0; s < 4; ++s) ap[s] = lv[s];
    }
    __syncthreads();
    #pragma unroll
    for (int t = 0; t < 4; ++t) {
        const int node = 64 * w + 16 * t + c;
        const bf16x8 a = *reinterpret_cast<const bf16x8*>(&Abuf[node * 40 + 8 * g]);
        #pragma unroll
        for (int nt = 0; nt < 2; ++nt)
            acc[t][nt] = __builtin_amdgcn_mfma_f32_16x16x32_bf16(a, Bh[nt], acc[t][nt], 0, 0, 0);
    }

    // ---- publish wave-boundary h2pre rows (nodes 64w and 64w+63) ----
    if (lane < 16) {
        edgebuf[w][0][c]      = acc[0][0][0];
        edgebuf[w][0][c + 16] = acc[0][1][0];
    } else if (lane >= 48) {
        edgebuf[w][1][c]      = acc[3][0][3];
        edgebuf[w][1][c + 16] = acc[3][1][3];
    }
    __syncthreads();

    // ---- stencil2 + relu + pool, directly on C/D-layout registers ----
    // Lane holds rows 64w+16t+4g+{0..3} for cols {c, c+16}. Neighbors of the
    // inner regs are in-register; group boundaries via shfl; wave boundaries
    // via edgebuf.
    float sum0 = 0.0f, sum1 = 0.0f;
    #pragma unroll
    for (int t = 0; t < 4; ++t) {
        const int nbase = 64 * w + 16 * t + 4 * g;
        float c0, l0, r0; gcn_coef(nbase + 0, c0, l0, r0);
        float c1, l1, r1; gcn_coef(nbase + 1, c1, l1, r1);
        float c2, l2, r2; gcn_coef(nbase + 2, c2, l2, r2);
        float c3, l3, r3; gcn_coef(nbase + 3, c3, l3, r3);
        #pragma unroll
        for (int nt = 0; nt < 2; ++nt) {
            const f32x4 v = acc[t][nt];
            // left neighbor of reg0 (node nbase-1)
            const float Lsame = __shfl(acc[t][nt][3], lane - 16, 64);             // g>0
            const float Lprev = __shfl(acc[(t > 0) ? t - 1 : 0][nt][3], c + 48, 64); // g==0,t>0
            float L = (g > 0) ? Lsame : Lprev;
            if (t == 0) {
                float eL = edgebuf[(w > 0) ? w - 1 : 0][1][c + 16 * nt];
                eL = (w > 0) ? eL : 0.0f;
                L = (g == 0) ? eL : L;
            }
            // right neighbor of reg3 (node nbase+4)
            const float Rsame = __shfl(acc[t][nt][0], lane + 16, 64);             // g<3
            const float Rnext = __shfl(acc[(t < 3) ? t + 1 : 3][nt][0], c, 64);   // g==3,t<3
            float R = (g < 3) ? Rsame : Rnext;
            if (t == 3) {
                float eR = edgebuf[(w < 3) ? w + 1 : 3][0][c + 16 * nt];
                eR = (w < 3) ? eR : 0.0f;
                R = (g == 3) ? eR : R;
            }
            const float bb = (nt == 0) ? b2v0 : b2v1;
            const float h0 = fmaxf(c0 * v[0] + l0 * L    + r0 * v[1] + bb, 0.0f);
            const float h1 = fmaxf(c1 * v[1] + l1 * v[0] + r1 * v[2] + bb, 0.0f);
            const float h2 = fmaxf(c2 * v[2] + l2 * v[1] + r2 * v[3] + bb, 0.0f);
            const float h3 = fmaxf(c3 * v[3] + l3 * v[2] + r3 * R    + bb, 0.0f);
            const float hs = (h0 + h1) + (h2 + h3);
            if (nt == 0) sum0 += hs; else sum1 += hs;
        }
    }
    // reduce the 4 row-groups (lanes differing in bits 4-5)
    sum0 += __shfl_xor(sum0, 16, 64); sum0 += __shfl_xor(sum0, 32, 64);
    sum1 += __shfl_xor(sum1, 16, 64); sum1 += __shfl_xor(sum1, 32, 64);
    if (g == 0) { waveparts[w][c] = sum0; waveparts[w][c + 16] = sum1; }
    __syncthreads();

    // ---- head: wave 0 only, shfl exchange, zero barriers. Waves 1-3 retire. ----
    if (i < 64) {
        // pooled[k] held by lane k (k<32); computed convergently (lanes 32-63 dup)
        const int kk = i & 31;
        const float pk_own = (waveparts[0][kk] + waveparts[1][kk] +
                              waveparts[2][kk] + waveparts[3][kk]) * (1.0f / 256.0f);
        float catv;
        if (i < HID) {
            float be = br[i];
            #pragma unroll 8
            for (int k = 0; k < HID; ++k)
                be = fmaf(__shfl(pk_own, k, 64), Wr[k * HID + i], be);
            catv = be;   // body_emb, no relu
        } else {
            const int cc = i - HID;
            float a = ba1[cc];
            a = fmaf(heads[2 * b],      Wa1[0 * HID + cc], a);
            a = fmaf(heads[2 * b + 1],  Wa1[1 * HID + cc], a);
            a = fmaf(body_sizes[b],     Wa1[2 * HID + cc], a);
            a = fmaf(fruits[2 * b],     Wa1[3 * HID + cc], a);
            a = fmaf(fruits[2 * b + 1], Wa1[4 * HID + cc], a);
            a = fmaxf(a, 0.0f);                    // aux1 in lanes 32-63
            float a2 = ba2[cc];
            #pragma unroll 8
            for (int k = 0; k < HID; ++k)
                a2 = fmaf(__shfl(a, HID + k, 64), Wa2[k * HID + cc], a2);
            catv = fmaxf(a2, 0.0f);                // aux2
        }
        float cb = bc[i];
        #pragma unroll 8
        for (int k = 0; k < FIN; ++k)
            cb = fmaf(__shfl(catv, k, 64), Wc[k * FIN + i], cb);
        cb = fmaxf(cb, 0.0f);
        float s0 = cb * Wp[i * 5 + 0];
        float s1 = cb * Wp[i * 5 + 1];
        float s2 = cb * Wp[i * 5 + 2];
        float s3 = cb * Wp[i * 5 + 3];
        float s4 = cb * Wp[i * 5 + 4];
        float s5 = cb * Wv[i];
        #pragma unroll
        for (int m = 1; m <= 32; m <<= 1) {
            s0 += __shfl_xor(s0, m, 64);
            s1 += __shfl_xor(s1, m, 64);
            s2 += __shfl_xor(s2, m, 64);
            s3 += __shfl_xor(s3, m, 64);
            s4 += __shfl_xor(s4, m, 64);
            s5 += __shfl_xor(s5, m, 64);
        }
        if (i == 0) {
            out[b * 5 + 0] = s0 + bp[0];
            out[b * 5 + 1] = s1 + bp[1];
            out[b * 5 + 2] = s2 + bp[2];
            out[b * 5 + 3] = s3 + bp[3];
            out[b * 5 + 4] = s4 + bp[4];
            out[NB * 5 + b] = s5 + bv[0];
        }
    }
}

extern "C" void kernel_launch(void* const* d_in, const int* in_sizes, int n_in,
                              void* d_out, int out_size, void* d_ws, size_t ws_size,
                              hipStream_t stream) {
    const float* x          = (const float*)d_in[0];
    const float* heads      = (const float*)d_in[1];
    const float* body_sizes = (const float*)d_in[2];
    const float* fruits     = (const float*)d_in[3];
    const float* W1 = (const float*)d_in[4];
    const float* b1 = (const float*)d_in[5];
    const float* W2 = (const float*)d_in[6];
    const float* b2 = (const float*)d_in[7];
    const float* Wr = (const float*)d_in[8];
    const float* br = (const float*)d_in[9];
    const float* Wa1 = (const float*)d_in[10];
    const float* ba1 = (const float*)d_in[11];
    const float* Wa2 = (const float*)d_in[12];
    const float* ba2 = (const float*)d_in[13];
    const float* Wc = (const float*)d_in[14];
    const float* bc = (const float*)d_in[15];
    const float* Wp = (const float*)d_in[16];
    const float* bp = (const float*)d_in[17];
    const float* Wv = (const float*)d_in[18];
    const float* bv = (const float*)d_in[19];

    float* out = (float*)d_out;
    snake_fused<<<NB, CL, 0, stream>>>(
        x, heads, body_sizes, fruits,
        W1, b1, W2, b2, Wr, br, Wa1, ba1, Wa2, ba2,
        Wc, bc, Wp, bp, Wv, bv, out);
}

// Round 5
// 126.825 us; speedup vs baseline: 1.2584x; 1.1168x over previous
//
#include <hip/hip_runtime.h>
#include <hip/hip_bf16.h>

// SnakeBrain fused kernel, round 5.
// R4 post-mortem: steady kernel ~40-45us (hidden below 43us poison fills in
// top-5). Remaining cost: serial wave-0 head (~170 dependent bpermutes),
// 6 barriers/snake of LDS A-frag round-trips (with 8-way bank conflicts,
// SQ_LDS_BANK_CONFLICT=524288), per-block B-fragment rebuild.
// Fix: 4 snakes/block (B amortized, heads run wave-parallel), A-frags built
// directly in registers via in-wave shfl (no Abuf, 1 barrier/snake),
// LDS-broadcast head, packed bf16 converts (v_cvt_pk_bf16_f32).

#define NB  4096
#define CL  256
#define HID 32
#define FIN 64
#define SPB 4     // snakes per block; grid = NB/SPB = 1024

typedef __attribute__((ext_vector_type(8))) short    bf16x8;
typedef __attribute__((ext_vector_type(4))) float    f32x4;
typedef __attribute__((ext_vector_type(4))) unsigned u32x4;

__device__ __forceinline__ unsigned pkbf(float a, float b) {
    // packs bf16(a) in low 16, bf16(b) in high 16 (RNE, v_cvt_pk_bf16_f32)
    __hip_bfloat162 hb = __float22bfloat162_rn(make_float2(a, b));
    unsigned u; __builtin_memcpy(&u, &hb, sizeof(u));
    return u;
}
__device__ __forceinline__ float bflo(unsigned u) { return __builtin_bit_cast(float, u << 16); }
__device__ __forceinline__ float bfhi(unsigned u) { return __builtin_bit_cast(float, u & 0xffff0000u); }

// GCN chain coefficients for node n (deg incl self-loop: 3 interior, 2 ends)
__device__ __forceinline__ void gcn_coef(int n, float& nc, float& nl, float& nr) {
    const float IS3 = 0.57735026918962576f, IS2 = 0.70710678118654752f;
    const float dn = (n == 0 || n == CL - 1) ? IS2 : IS3;
    nc = dn * dn;
    nl = (n > 0)      ? dn * ((n == 1)      ? IS2 : IS3) : 0.0f;
    nr = (n < CL - 1) ? dn * ((n == CL - 2) ? IS2 : IS3) : 0.0f;
}

__global__ __launch_bounds__(256, 4) void snake_fused(
    const float* __restrict__ x,
    const float* __restrict__ heads,
    const float* __restrict__ body_sizes,
    const float* __restrict__ fruits,
    const float* __restrict__ W1, const float* __restrict__ b1,
    const float* __restrict__ W2, const float* __restrict__ b2,
    const float* __restrict__ Wr, const float* __restrict__ br,
    const float* __restrict__ Wa1, const float* __restrict__ ba1,
    const float* __restrict__ Wa2, const float* __restrict__ ba2,
    const float* __restrict__ Wc, const float* __restrict__ bc,
    const float* __restrict__ Wp, const float* __restrict__ bp,
    const float* __restrict__ Wv, const float* __restrict__ bv,
    float* __restrict__ out)
{
    __shared__ __align__(16) float edgebuf[SPB][4][2][HID];  // [s][wave][L/R][ch] 4 KB
    __shared__ __align__(16) float waveparts[SPB][HID][4];   // [s][ch][wave]      2 KB
    __shared__ __align__(16) float poolLDS[SPB][HID];
    __shared__ __align__(16) float auxLDS[SPB][HID];
    __shared__ __align__(16) float catLDS[SPB][FIN];

    const int blk  = blockIdx.x;
    const int i    = threadIdx.x;     // natural node index within a snake
    const int w    = i >> 6;          // wave: nodes 64w..64w+63
    const int lane = i & 63;
    const int g    = lane >> 4;       // k-group (A) / row-group (C)
    const int c    = lane & 15;       // tile col

    // ---- B fragments for W2 (split bf16), built once per block ----
    // B layout: B[k=8g+j][n=c+16nt]
    bf16x8 Bh[2], Bl[2];
    #pragma unroll
    for (int nt = 0; nt < 2; ++nt) {
        unsigned hh[4], ll[4];
        #pragma unroll
        for (int p = 0; p < 4; ++p) {
            const float wa = W2[(8 * g + 2 * p)     * HID + c + 16 * nt];
            const float wb = W2[(8 * g + 2 * p + 1) * HID + c + 16 * nt];
            const unsigned hu = pkbf(wa, wb);
            hh[p] = hu;
            ll[p] = pkbf(wa - bflo(hu), wb - bfhi(hu));
        }
        u32x4 H = {hh[0], hh[1], hh[2], hh[3]};
        u32x4 L = {ll[0], ll[1], ll[2], ll[3]};
        Bh[nt] = __builtin_bit_cast(bf16x8, H);
        Bl[nt] = __builtin_bit_cast(bf16x8, L);
    }
    const float b2v0 = b2[c], b2v1 = b2[c + 16];

    // W1/b1 slices for this lane's A-channels 8g..8g+7
    const float4 W1a0 = *reinterpret_cast<const float4*>(W1 + 8 * g);
    const float4 W1a1 = *reinterpret_cast<const float4*>(W1 + 8 * g + 4);
    const float4 W1b0 = *reinterpret_cast<const float4*>(W1 + HID + 8 * g);
    const float4 W1b1 = *reinterpret_cast<const float4*>(W1 + HID + 8 * g + 4);
    const float4 b1v0 = *reinterpret_cast<const float4*>(b1 + 8 * g);
    const float4 b1v1 = *reinterpret_cast<const float4*>(b1 + 8 * g + 4);

    // stencil-1 coefficients for natural node i (snake-independent)
    float ncd, nld, nrd;
    gcn_coef(i, ncd, nld, nrd);

    const float THIRD = 0.33333333333333333f;
    const float I23   = 0.40824829046386302f;   // 1/sqrt(6)
    const bool fixL = (w == 0) && (g == 0);     // lanes owning nodes 0..3 rows
    const bool fixR = (w == 3) && (g == 3);     // lanes owning nodes 252..255

    // ================= main loop over SPB snakes =================
    #pragma unroll 1
    for (int s = 0; s < SPB; ++s) {
        const int gs = SPB * blk + s;
        const float2* xs = reinterpret_cast<const float2*>(x) + gs * CL;

        // stencil on 2-ch input x (S and W1 commute), natural layout
        const float2 xc = xs[i];
        const float2 xl = xs[i - (i > 0)];
        const float2 xr = xs[i + (i < CL - 1)];
        const float sxx = ncd * xc.x + nld * xl.x + nrd * xr.x;
        const float sxy = ncd * xc.y + nld * xl.y + nrd * xr.y;

        // gather Sx for this lane's A-nodes 64w+16t+c (lane 16t+c holds it)
        float sxA[4], syA[4];
        #pragma unroll
        for (int t = 0; t < 4; ++t) {
            sxA[t] = __shfl(sxx, 16 * t + c, 64);
            syA[t] = __shfl(sxy, 16 * t + c, 64);
        }

        // per-tile: r1 channels 8g..8g+7 of node 16t+c -> bf16 split -> MFMA
        f32x4 acc[4][2];
        #pragma unroll
        for (int t = 0; t < 4; ++t)
            #pragma unroll
            for (int nt = 0; nt < 2; ++nt) { f32x4 z = {0.f, 0.f, 0.f, 0.f}; acc[t][nt] = z; }

        #pragma unroll
        for (int t = 0; t < 4; ++t) {
            const float sa = sxA[t], sb = syA[t];
            const float r0 = fmaxf(fmaf(sa, W1a0.x, fmaf(sb, W1b0.x, b1v0.x)), 0.f);
            const float r1 = fmaxf(fmaf(sa, W1a0.y, fmaf(sb, W1b0.y, b1v0.y)), 0.f);
            const float r2 = fmaxf(fmaf(sa, W1a0.z, fmaf(sb, W1b0.z, b1v0.z)), 0.f);
            const float r3 = fmaxf(fmaf(sa, W1a0.w, fmaf(sb, W1b0.w, b1v0.w)), 0.f);
            const float r4 = fmaxf(fmaf(sa, W1a1.x, fmaf(sb, W1b1.x, b1v1.x)), 0.f);
            const float r5 = fmaxf(fmaf(sa, W1a1.y, fmaf(sb, W1b1.y, b1v1.y)), 0.f);
            const float r6 = fmaxf(fmaf(sa, W1a1.z, fmaf(sb, W1b1.z, b1v1.z)), 0.f);
            const float r7 = fmaxf(fmaf(sa, W1a1.w, fmaf(sb, W1b1.w, b1v1.w)), 0.f);
            const unsigned h0 = pkbf(r0, r1), h1 = pkbf(r2, r3);
            const unsigned h2 = pkbf(r4, r5), h3 = pkbf(r6, r7);
            const unsigned q0 = pkbf(r0 - bflo(h0), r1 - bfhi(h0));
            const unsigned q1 = pkbf(r2 - bflo(h1), r3 - bfhi(h1));
            const unsigned q2 = pkbf(r4 - bflo(h2), r5 - bfhi(h2));
            const unsigned q3 = pkbf(r6 - bflo(h3), r7 - bfhi(h3));
            u32x4 HU = {h0, h1, h2, h3};
            u32x4 LU = {q0, q1, q2, q3};
            const bf16x8 ah = __builtin_bit_cast(bf16x8, HU);
            const bf16x8 al = __builtin_bit_cast(bf16x8, LU);
            #pragma unroll
            for (int nt = 0; nt < 2; ++nt) {
                acc[t][nt] = __builtin_amdgcn_mfma_f32_16x16x32_bf16(ah, Bh[nt], acc[t][nt], 0, 0, 0);
                acc[t][nt] = __builtin_amdgcn_mfma_f32_16x16x32_bf16(al, Bh[nt], acc[t][nt], 0, 0, 0);
                acc[t][nt] = __builtin_amdgcn_mfma_f32_16x16x32_bf16(ah, Bl[nt], acc[t][nt], 0, 0, 0);
            }
        }

        // publish wave-boundary h2pre rows (nodes 64w and 64w+63)
        if (lane < 16) {
            edgebuf[s][w][0][c]      = acc[0][0][0];
            edgebuf[s][w][0][c + 16] = acc[0][1][0];
        } else if (lane >= 48) {
            edgebuf[s][w][1][c]      = acc[3][0][3];
            edgebuf[s][w][1][c + 16] = acc[3][1][3];
        }
        __syncthreads();   // the single per-snake barrier

        // stencil2 + relu + mean-pool on C/D-layout regs
        // C/D: lane holds nodes 64w+16t+4g+{0..3} at channels {c, c+16}
        float sum0 = 0.f, sum1 = 0.f;
        #pragma unroll
        for (int t = 0; t < 4; ++t) {
            float c0 = THIRD, r0c = THIRD, l1c = THIRD;
            float c3 = THIRD, l3c = THIRD, r2c = THIRD;
            if (t == 0) { c0 = fixL ? 0.5f : THIRD; r0c = fixL ? I23 : THIRD; l1c = fixL ? I23 : THIRD; }
            if (t == 3) { c3 = fixR ? 0.5f : THIRD; l3c = fixR ? I23 : THIRD; r2c = fixR ? I23 : THIRD; }
            #pragma unroll
            for (int nt = 0; nt < 2; ++nt) {
                const f32x4 v = acc[t][nt];
                // left neighbor of reg0: sender role g==3 provides acc[t-1][3]
                const float Lsend = (g == 3) ? acc[(t > 0) ? t - 1 : 0][nt][3] : acc[t][nt][3];
                const int   Lsrc  = (g == 0) ? (c + 48) : (lane - 16);
                float L = __shfl(Lsend, Lsrc, 64);
                if (t == 0) {
                    float eL = edgebuf[s][(w > 0) ? w - 1 : 0][1][c + 16 * nt];
                    eL = (w > 0) ? eL : 0.f;
                    L = (g == 0) ? eL : L;
                }
                // right neighbor of reg3: sender role g==0 provides acc[t+1][0]
                const float Rsend = (g == 0) ? acc[(t < 3) ? t + 1 : 3][nt][0] : acc[t][nt][0];
                const int   Rsrc  = (g == 3) ? c : (lane + 16);
                float R = __shfl(Rsend, Rsrc, 64);
                if (t == 3) {
                    float eR = edgebuf[s][(w < 3) ? w + 1 : 3][0][c + 16 * nt];
                    eR = (w < 3) ? eR : 0.f;
                    R = (g == 3) ? eR : R;
                }
                const float bb = (nt == 0) ? b2v0 : b2v1;
                const float h0 = fmaxf(fmaf(c0,    v[0], fmaf(THIRD, L,    fmaf(r0c,  v[1], bb))), 0.f);
                const float h1 = fmaxf(fmaf(THIRD, v[1], fmaf(l1c,   v[0], fmaf(THIRD, v[2], bb))), 0.f);
                const float h2 = fmaxf(fmaf(THIRD, v[2], fmaf(THIRD, v[1], fmaf(r2c,  v[3], bb))), 0.f);
                const float h3 = fmaxf(fmaf(c3,    v[3], fmaf(l3c,   v[2], fmaf(THIRD, R,   bb))), 0.f);
                const float hs = (h0 + h1) + (h2 + h3);
                if (nt == 0) sum0 += hs; else sum1 += hs;
            }
        }
        sum0 += __shfl_xor(sum0, 16, 64); sum0 += __shfl_xor(sum0, 32, 64);
        sum1 += __shfl_xor(sum1, 16, 64); sum1 += __shfl_xor(sum1, 32, 64);
        if (g == 0) {   // lanes 0..15
            waveparts[s][c][w]      = sum0;
            waveparts[s][c + 16][w] = sum1;
        }
    }
    __syncthreads();   // all snakes' waveparts visible

    // ================= head: wave w handles snake w =================
    const int gsH = SPB * blk + w;
    if (lane < HID) {
        const f32x4 wp = *reinterpret_cast<const f32x4*>(&waveparts[w][lane][0]);
        poolLDS[w][lane] = (wp.x + wp.y + wp.z + wp.w) * (1.0f / CL);
    } else {
        const int cc = lane - HID;
        float a = ba1[cc];
        a = fmaf(heads[2 * gsH],      Wa1[0 * HID + cc], a);
        a = fmaf(heads[2 * gsH + 1],  Wa1[1 * HID + cc], a);
        a = fmaf(body_sizes[gsH],     Wa1[2 * HID + cc], a);
        a = fmaf(fruits[2 * gsH],     Wa1[3 * HID + cc], a);
        a = fmaf(fruits[2 * gsH + 1], Wa1[4 * HID + cc], a);
        auxLDS[w][cc] = fmaxf(a, 0.f);
    }
    __syncthreads();

    if (lane < HID) {     // body_emb = pooled @ Wr + br (no relu)
        float be0 = br[lane], be1 = 0.f;
        const float4* p4 = reinterpret_cast<const float4*>(poolLDS[w]);
        #pragma unroll
        for (int k4 = 0; k4 < 8; ++k4) {
            const float4 p = p4[k4];
            be0 = fmaf(p.x, Wr[(4 * k4 + 0) * HID + lane], be0);
            be1 = fmaf(p.y, Wr[(4 * k4 + 1) * HID + lane], be1);
            be0 = fmaf(p.z, Wr[(4 * k4 + 2) * HID + lane], be0);
            be1 = fmaf(p.w, Wr[(4 * k4 + 3) * HID + lane], be1);
        }
        catLDS[w][lane] = be0 + be1;
    } else {              // aux2 = relu(aux1 @ Wa2 + ba2)
        const int cc = lane - HID;
        float a0 = ba2[cc], a1 = 0.f;
        const float4* p4 = reinterpret_cast<const float4*>(auxLDS[w]);
        #pragma unroll
        for (int k4 = 0; k4 < 8; ++k4) {
            const float4 p = p4[k4];
            a0 = fmaf(p.x, Wa2[(4 * k4 + 0) * HID + cc], a0);
            a1 = fmaf(p.y, Wa2[(4 * k4 + 1) * HID + cc], a1);
            a0 = fmaf(p.z, Wa2[(4 * k4 + 2) * HID + cc], a0);
            a1 = fmaf(p.w, Wa2[(4 * k4 + 3) * HID + cc], a1);
        }
        catLDS[w][lane] = fmaxf(a0 + a1, 0.f);
    }
    __syncthreads();

    // combined = relu(cat @ Wc + bc); then logits/value via butterfly
    {
        float cb0 = bc[lane], cb1 = 0.f;
        const float4* c4p = reinterpret_cast<const float4*>(catLDS[w]);
        #pragma unroll
        for (int k4 = 0; k4 < 16; ++k4) {
            const float4 p = c4p[k4];
            cb0 = fmaf(p.x, Wc[(4 * k4 + 0) * FIN + lane], cb0);
            cb1 = fmaf(p.y, Wc[(4 * k4 + 1) * FIN + lane], cb1);
            cb0 = fmaf(p.z, Wc[(4 * k4 + 2) * FIN + lane], cb0);
            cb1 = fmaf(p.w, Wc[(4 * k4 + 3) * FIN + lane], cb1);
        }
        const float cb = fmaxf(cb0 + cb1, 0.f);
        float s0 = cb * Wp[lane * 5 + 0];
        float s1 = cb * Wp[lane * 5 + 1];
        float s2 = cb * Wp[lane * 5 + 2];
        float s3 = cb * Wp[lane * 5 + 3];
        float s4 = cb * Wp[lane * 5 + 4];
        float s5 = cb * Wv[lane];
        #pragma unroll
        for (int m = 1; m <= 32; m <<= 1) {
            s0 += __shfl_xor(s0, m, 64);
            s1 += __shfl_xor(s1, m, 64);
            s2 += __shfl_xor(s2, m, 64);
            s3 += __shfl_xor(s3, m, 64);
            s4 += __shfl_xor(s4, m, 64);
            s5 += __shfl_xor(s5, m, 64);
        }
        if (lane == 0) {
            out[gsH * 5 + 0] = s0 + bp[0];
            out[gsH * 5 + 1] = s1 + bp[1];
            out[gsH * 5 + 2] = s2 + bp[2];
            out[gsH * 5 + 3] = s3 + bp[3];
            out[gsH * 5 + 4] = s4 + bp[4];
            out[NB * 5 + gsH] = s5 + bv[0];
        }
    }
}

extern "C" void kernel_launch(void* const* d_in, const int* in_sizes, int n_in,
                              void* d_out, int out_size, void* d_ws, size_t ws_size,
                              hipStream_t stream) {
    const float* x          = (const float*)d_in[0];
    const float* heads      = (const float*)d_in[1];
    const float* body_sizes = (const float*)d_in[2];
    const float* fruits     = (const float*)d_in[3];
    const float* W1 = (const float*)d_in[4];
    const float* b1 = (const float*)d_in[5];
    const float* W2 = (const float*)d_in[6];
    const float* b2 = (const float*)d_in[7];
    const float* Wr = (const float*)d_in[8];
    const float* br = (const float*)d_in[9];
    const float* Wa1 = (const float*)d_in[10];
    const float* ba1 = (const float*)d_in[11];
    const float* Wa2 = (const float*)d_in[12];
    const float* ba2 = (const float*)d_in[13];
    const float* Wc = (const float*)d_in[14];
    const float* bc = (const float*)d_in[15];
    const float* Wp = (const float*)d_in[16];
    const float* bp = (const float*)d_in[17];
    const float* Wv = (const float*)d_in[18];
    const float* bv = (const float*)d_in[19];

    float* out = (float*)d_out;
    snake_fused<<<NB / SPB, CL, 0, stream>>>(
        x, heads, body_sizes, fruits,
        W1, b1, W2, b2, Wr, br, Wa1, ba1, Wa2, ba2,
        Wc, bc, Wp, bp, Wv, bv, out);
}